// Round 7
// baseline (440.392 us; speedup 1.0000x reference)
//
#include <hip/hip_runtime.h>
#include <math.h>

#define NN 2048
#define HID 128
#define HID2 64
#define NP ((NN*(NN-1))/2)   // 2096128

typedef __bf16 bf16x8 __attribute__((ext_vector_type(8)));
typedef float  f32x4  __attribute__((ext_vector_type(4)));

// Kernel 1: per node row: h = relu(X@Wt+bt); a = h@W1top + b1; b = h@W1bot.
// Emits Abf (bf16 row-major), Bp (bf16 MFMA-fragment-packed), and per-row
// stats sa/sb computed from the bf16-ROUNDED values (self-consistent with
// what kernel 2 actually sums).
__global__ __launch_bounds__(128) void precompute_AB(
    const float* __restrict__ X, const float* __restrict__ Wt, const float* __restrict__ bt,
    const float* __restrict__ W1, const float* __restrict__ b1,
    __bf16* __restrict__ Abf, __bf16* __restrict__ Bp,
    float2* __restrict__ sa, float2* __restrict__ sb)
{
    __shared__ float x_s[HID];
    __shared__ float h_s[HID];
    __shared__ float red[2][4];
    const int row = blockIdx.x;
    const int c = threadIdx.x;
    x_s[c] = X[row*HID + c];
    __syncthreads();
    float hc = bt[c];
    #pragma unroll 8
    for (int k = 0; k < HID; ++k) hc = fmaf(x_s[k], Wt[k*HID + c], hc);
    h_s[c] = fmaxf(hc, 0.f);
    __syncthreads();
    float a = b1[c];
    float bsum = 0.f;
    #pragma unroll 8
    for (int k = 0; k < HID; ++k) {
        float hk = h_s[k];
        a    = fmaf(hk, W1[k*HID + c], a);
        bsum = fmaf(hk, W1[(HID + k)*HID + c], bsum);
    }
    const __bf16 ab = (__bf16)a;
    const __bf16 bb = (__bf16)bsum;
    Abf[row*HID + c] = ab;
    // fragment-packed B: element (row, k=c): ks=c>>5, g4=(c>>3)&3, e=c&7
    {
        const int ks = c >> 5, g4 = (c >> 3) & 3, e = c & 7;
        Bp[(((size_t)(row >> 4)*4 + ks)*64 + g4*16 + (row & 15))*8 + e] = bb;
    }
    const float ar = (float)ab;
    const float br = (float)bb;
    float r0 = ar, r1 = ar*ar, r2 = br, r3 = br*br;
    #pragma unroll
    for (int m = 1; m <= 32; m <<= 1) {
        r0 += __shfl_xor(r0, m); r1 += __shfl_xor(r1, m);
        r2 += __shfl_xor(r2, m); r3 += __shfl_xor(r3, m);
    }
    if ((c & 63) == 0) {
        red[c >> 6][0] = r0; red[c >> 6][1] = r1; red[c >> 6][2] = r2; red[c >> 6][3] = r3;
    }
    __syncthreads();
    if (c == 0) {
        sa[row] = make_float2(red[0][0] + red[1][0], red[0][1] + red[1][1]);
        sb[row] = make_float2(red[0][2] + red[1][2], red[0][3] + red[1][3]);
    }
}

// Kernel 1b: pack W2 (fp32 [128][64]) into bf16 fragment order (A-operand).
__global__ __launch_bounds__(256) void pack_W2(const float* __restrict__ W2,
                                               __bf16* __restrict__ W2p)
{
    const int t = threadIdx.x;
    for (int fs = t; fs < 16*64; fs += 256) {
        const int frag = fs >> 6, lane = fs & 63;
        const int ks = frag >> 2, nt = frag & 3;
        const int kbase = ks*32 + (lane >> 4)*8;
        const int col   = nt*16 + (lane & 15);
        #pragma unroll
        for (int e = 0; e < 8; ++e)
            W2p[fs*8 + e] = (__bf16)W2[(kbase + e)*HID2 + col];
    }
}

// Kernel 1c: pair_index is a pure function of indices.
__global__ __launch_bounds__(256) void fill_pi(float* __restrict__ pi)
{
    const int i = blockIdx.x;
    const size_t off = (size_t)i*(NN-1) - (size_t)i*(i-1)/2;
    const int cnt = NN - 1 - i;
    for (int t = threadIdx.x; t < cnt; t += 256) {
        pi[off + t]      = (float)i;
        pi[NP + off + t] = (float)(i + 1 + t);
    }
}

// Kernel 2: 256 threads (4 waves), 4 sub-blocks of 16 pairs per wave, fully
// unrolled; per-sub epilogue keeps acc live-set small. launch_bounds(256,4)
// -> 128-VGPR cap (no spill tier).
__global__ __launch_bounds__(256, 4) void pairs_mfma(
    const __bf16* __restrict__ Abf, const __bf16* __restrict__ Bp,
    const float2* __restrict__ sa, const float2* __restrict__ sb,
    const float* __restrict__ ln_g, const float* __restrict__ ln_b,
    const __bf16* __restrict__ W2p, const float* __restrict__ b2,
    const float* __restrict__ W3, const float* __restrict__ b3,
    float* __restrict__ out)
{
    // decode linear tile id -> (i, jb) over upper-triangular 256x256 tiles
    int t = blockIdx.x;
    int q = 0, base = 0;
    while (q < 7 && t >= base + 256*(8 - q)) { base += 256*(8 - q); ++q; }
    const int idx = t - base;
    const int den = 8 - q;
    const int i  = (q << 8) + idx / den;
    const int jb = q + idx % den;

    const int w    = threadIdx.x >> 6;
    const int lane = threadIdx.x & 63;
    const int jw0  = (jb << 8) + (w << 6);       // this wave's 64 j's
    if (jw0 + 63 < i) return;                    // keep the diag wave alive

    const int p16 = lane & 15;
    const int g4  = lane >> 4;

    // A fragments (bf16, broadcast across pair-rows), read once
    bf16x8 abf[4];
    #pragma unroll
    for (int ks = 0; ks < 4; ++ks)
        abf[ks] = *(const bf16x8*)(Abf + (size_t)i*HID + ks*32 + g4*8);
    const float2 sav = sa[i];

    // hoist LN affine params (same 8 elems per lane every sub)
    f32x4 gv[4][2], lv[4][2];
    #pragma unroll
    for (int ks = 0; ks < 4; ++ks) {
        const int kb = ks*32 + g4*8;
        gv[ks][0] = *(const f32x4*)(ln_g + kb);
        gv[ks][1] = *(const f32x4*)(ln_g + kb + 4);
        lv[ks][0] = *(const f32x4*)(ln_b + kb);
        lv[ks][1] = *(const f32x4*)(ln_b + kb + 4);
    }

    const bf16x8* __restrict__ Bpv = (const bf16x8*)Bp;
    float* probs = out;
    float* adj   = out + 3*(size_t)NP;
    const float b3v = b3[0];

    #pragma unroll
    for (int s = 0; s < 4; ++s) {
        const int j16 = jw0 + s*16;

        // B fragments for these 16 pairs (coalesced 16B/lane, L2)
        bf16x8 bfr[4];
        const size_t fb = ((size_t)(j16 >> 4))*4;
        #pragma unroll
        for (int ks = 0; ks < 4; ++ks) bfr[ks] = Bpv[(fb + ks)*64 + lane];

        // dot(A[i], B[j_p]) via broadcast-A MFMA, 2 chains of 2
        f32x4 d0 = (f32x4){0.f,0.f,0.f,0.f};
        f32x4 d1 = (f32x4){0.f,0.f,0.f,0.f};
        d0 = __builtin_amdgcn_mfma_f32_16x16x32_bf16(abf[0], bfr[0], d0, 0, 0, 0);
        d1 = __builtin_amdgcn_mfma_f32_16x16x32_bf16(abf[1], bfr[1], d1, 0, 0, 0);
        d0 = __builtin_amdgcn_mfma_f32_16x16x32_bf16(abf[2], bfr[2], d0, 0, 0, 0);
        d1 = __builtin_amdgcn_mfma_f32_16x16x32_bf16(abf[3], bfr[3], d1, 0, 0, 0);

        // O(1) LN stats for this lane's pair
        const float2 sbv = sb[j16 + p16];
        const float mu   = (sav.x + sbv.x) * (1.f/HID);
        const float ez2  = (sav.y + sbv.y + 2.f*(d0[0] + d1[0])) * (1.f/HID);
        const float rstd = rsqrtf(ez2 - mu*mu + 1e-5f);
        const float v    = -mu * rstd;

        // zn = relu(g*(rstd*z + v) + l), z = a_bf16 + b_bf16; 16 MFMAs
        f32x4 acc[4];
        #pragma unroll
        for (int nt = 0; nt < 4; ++nt) acc[nt] = (f32x4){0.f,0.f,0.f,0.f};
        #pragma unroll
        for (int ks = 0; ks < 4; ++ks) {
            bf16x8 af;
            #pragma unroll
            for (int e = 0; e < 4; ++e) {
                float z0 = (float)abf[ks][e]   + (float)bfr[ks][e];
                float z1 = (float)abf[ks][4+e] + (float)bfr[ks][4+e];
                float q0 = fmaf(rstd, z0, v);
                float q1 = fmaf(rstd, z1, v);
                af[e]   = (__bf16)fmaxf(fmaf(gv[ks][0][e], q0, lv[ks][0][e]), 0.f);
                af[4+e] = (__bf16)fmaxf(fmaf(gv[ks][1][e], q1, lv[ks][1][e]), 0.f);
            }
            #pragma unroll
            for (int nt = 0; nt < 4; ++nt) {
                bf16x8 wf = *(const bf16x8*)(W2p + ((size_t)((ks*4 + nt)*64 + lane)) * 8);
                acc[nt] = __builtin_amdgcn_mfma_f32_16x16x32_bf16(wf, af, acc[nt], 0, 0, 0);
            }
        }

        // epilogue: lane holds channels (nt*16 + g4*4 + r) of pair p16
        float part = 0.f;
        #pragma unroll
        for (int nt = 0; nt < 4; ++nt) {
            f32x4 b2v = *(const f32x4*)(b2 + nt*16 + g4*4);
            f32x4 w3v = *(const f32x4*)(W3 + nt*16 + g4*4);
            #pragma unroll
            for (int r = 0; r < 4; ++r)
                part = fmaf(fmaxf(acc[nt][r] + b2v[r], 0.f), w3v[r], part);
        }
        part += __shfl_xor(part, 16);
        part += __shfl_xor(part, 32);

        if (g4 == 0) {
            const int j = j16 + p16;
            if (j == i) {
                adj[(size_t)i*NN + i] = 0.f;
            } else if (j > i) {
                const float pr = 1.f / (1.f + __expf(-(part + b3v)));
                const int kpair = i*(NN-1) - (i*(i-1))/2 + (j - i - 1);
                probs[kpair] = pr;
                adj[(size_t)i*NN + j] = pr;
                adj[(size_t)j*NN + i] = pr;
            }
        }
    }
}

extern "C" void kernel_launch(void* const* d_in, const int* in_sizes, int n_in,
                              void* d_out, int out_size, void* d_ws, size_t ws_size,
                              hipStream_t stream) {
    const float* X    = (const float*)d_in[0];
    const float* Wt   = (const float*)d_in[1];
    const float* bt   = (const float*)d_in[2];
    const float* W1   = (const float*)d_in[3];
    const float* b1   = (const float*)d_in[4];
    const float* ln_g = (const float*)d_in[5];
    const float* ln_b = (const float*)d_in[6];
    const float* W2   = (const float*)d_in[7];
    const float* b2   = (const float*)d_in[8];
    const float* W3   = (const float*)d_in[9];
    const float* b3   = (const float*)d_in[10];
    float* out = (float*)d_out;

    float2* sa  = (float2*)d_ws;                       // 2048 float2 (16KB)
    float2* sb  = sa + NN;                             // 16KB
    __bf16* Abf = (__bf16*)(sb + NN);                  // 2048*128 bf16 (512KB)
    __bf16* Bp  = Abf + (size_t)NN * HID;              // 512KB (packed)
    __bf16* W2p = Bp  + (size_t)NN * HID;              // 16KB

    precompute_AB<<<NN, HID, 0, stream>>>(X, Wt, bt, W1, b1, Abf, Bp, sa, sb);
    pack_W2<<<1, 256, 0, stream>>>(W2, W2p);
    fill_pi<<<NN-1, 256, 0, stream>>>(out + NP);

    const int nblk = 256 * 36;
    pairs_mfma<<<nblk, 256, 0, stream>>>(Abf, Bp, sa, sb, ln_g, ln_b, W2p, b2, W3, b3, out);
}

// Round 8
// 138.130 us; speedup vs baseline: 3.1882x; 3.1882x over previous
//
#include <hip/hip_runtime.h>
#include <math.h>

#define NN 2048
#define HID 128
#define HID2 64
#define NP ((NN*(NN-1))/2)   // 2096128

typedef __bf16 bf16x8 __attribute__((ext_vector_type(8)));
typedef float  f32x4  __attribute__((ext_vector_type(4)));

// Kernel 1: per node row: h = relu(X@Wt+bt); a = h@W1top + b1; b = h@W1bot.
// Emits Abf (bf16 row-major), Bp (bf16 MFMA-fragment-packed), and per-row
// stats sa/sb computed from the bf16-ROUNDED values.
__global__ __launch_bounds__(128) void precompute_AB(
    const float* __restrict__ X, const float* __restrict__ Wt, const float* __restrict__ bt,
    const float* __restrict__ W1, const float* __restrict__ b1,
    __bf16* __restrict__ Abf, __bf16* __restrict__ Bp,
    float2* __restrict__ sa, float2* __restrict__ sb)
{
    __shared__ float x_s[HID];
    __shared__ float h_s[HID];
    __shared__ float red[2][4];
    const int row = blockIdx.x;
    const int c = threadIdx.x;
    x_s[c] = X[row*HID + c];
    __syncthreads();
    float hc = bt[c];
    #pragma unroll 8
    for (int k = 0; k < HID; ++k) hc = fmaf(x_s[k], Wt[k*HID + c], hc);
    h_s[c] = fmaxf(hc, 0.f);
    __syncthreads();
    float a = b1[c];
    float bsum = 0.f;
    #pragma unroll 8
    for (int k = 0; k < HID; ++k) {
        float hk = h_s[k];
        a    = fmaf(hk, W1[k*HID + c], a);
        bsum = fmaf(hk, W1[(HID + k)*HID + c], bsum);
    }
    const __bf16 ab = (__bf16)a;
    const __bf16 bb = (__bf16)bsum;
    Abf[row*HID + c] = ab;
    {
        const int ks = c >> 5, g4 = (c >> 3) & 3, e = c & 7;
        Bp[(((size_t)(row >> 4)*4 + ks)*64 + g4*16 + (row & 15))*8 + e] = bb;
    }
    const float ar = (float)ab;
    const float br = (float)bb;
    float r0 = ar, r1 = ar*ar, r2 = br, r3 = br*br;
    #pragma unroll
    for (int m = 1; m <= 32; m <<= 1) {
        r0 += __shfl_xor(r0, m); r1 += __shfl_xor(r1, m);
        r2 += __shfl_xor(r2, m); r3 += __shfl_xor(r3, m);
    }
    if ((c & 63) == 0) {
        red[c >> 6][0] = r0; red[c >> 6][1] = r1; red[c >> 6][2] = r2; red[c >> 6][3] = r3;
    }
    __syncthreads();
    if (c == 0) {
        sa[row] = make_float2(red[0][0] + red[1][0], red[0][1] + red[1][1]);
        sb[row] = make_float2(red[0][2] + red[1][2], red[0][3] + red[1][3]);
    }
}

// Kernel 1b: pack W2 (fp32 [128][64]) into bf16 fragment order (A-operand).
__global__ __launch_bounds__(256) void pack_W2(const float* __restrict__ W2,
                                               __bf16* __restrict__ W2p)
{
    const int t = threadIdx.x;
    for (int fs = t; fs < 16*64; fs += 256) {
        const int frag = fs >> 6, lane = fs & 63;
        const int ks = frag >> 2, nt = frag & 3;
        const int kbase = ks*32 + (lane >> 4)*8;
        const int col   = nt*16 + (lane & 15);
        #pragma unroll
        for (int e = 0; e < 8; ++e)
            W2p[fs*8 + e] = (__bf16)W2[(kbase + e)*HID2 + col];
    }
}

// Kernel 1c: pair_index is a pure function of indices.
__global__ __launch_bounds__(256) void fill_pi(float* __restrict__ pi)
{
    const int i = blockIdx.x;
    const size_t off = (size_t)i*(NN-1) - (size_t)i*(i-1)/2;
    const int cnt = NN - 1 - i;
    for (int t = threadIdx.x; t < cnt; t += 256) {
        pi[off + t]      = (float)i;
        pi[NP + off + t] = (float)(i + 1 + t);
    }
}

// Kernel 2: 256 threads (4 waves), 4 sub-blocks of 16 pairs per wave.
// W2 fragments staged in LDS once per block; launch_bounds(256,3) = the
// empirically spill-free allocation regime (round 5: VGPR 84, no spill).
__global__ __launch_bounds__(256, 3) void pairs_mfma(
    const __bf16* __restrict__ Abf, const __bf16* __restrict__ Bp,
    const float2* __restrict__ sa, const float2* __restrict__ sb,
    const float* __restrict__ ln_g, const float* __restrict__ ln_b,
    const __bf16* __restrict__ W2p, const float* __restrict__ b2,
    const float* __restrict__ W3, const float* __restrict__ b3,
    float* __restrict__ out)
{
    __shared__ bf16x8 w2s[16*64];            // 16 KB: all W2 fragments

    // cooperative stage (before any exit so the barrier is uniform)
    {
        const bf16x8* __restrict__ W2v = (const bf16x8*)W2p;
        #pragma unroll
        for (int t = 0; t < 4; ++t)
            w2s[t*256 + threadIdx.x] = W2v[t*256 + threadIdx.x];
    }

    // decode linear tile id -> (i, jb) over upper-triangular 256x256 tiles
    int t = blockIdx.x;
    int q = 0, base = 0;
    while (q < 7 && t >= base + 256*(8 - q)) { base += 256*(8 - q); ++q; }
    const int idx = t - base;
    const int den = 8 - q;
    const int i  = (q << 8) + idx / den;
    const int jb = q + idx % den;

    __syncthreads();

    const int w    = threadIdx.x >> 6;
    const int lane = threadIdx.x & 63;
    const int jw0  = (jb << 8) + (w << 6);       // this wave's 64 j's
    if (jw0 + 63 < i) return;                    // keep the diag wave alive

    const int p16 = lane & 15;
    const int g4  = lane >> 4;

    // A fragments (bf16, broadcast across pair-rows), read once
    bf16x8 abf[4];
    #pragma unroll
    for (int ks = 0; ks < 4; ++ks)
        abf[ks] = *(const bf16x8*)(Abf + (size_t)i*HID + ks*32 + g4*8);
    const float2 sav = sa[i];

    // hoist LN affine params (same 8 elems per lane every sub)
    f32x4 gv[4][2], lv[4][2];
    #pragma unroll
    for (int ks = 0; ks < 4; ++ks) {
        const int kb = ks*32 + g4*8;
        gv[ks][0] = *(const f32x4*)(ln_g + kb);
        gv[ks][1] = *(const f32x4*)(ln_g + kb + 4);
        lv[ks][0] = *(const f32x4*)(ln_b + kb);
        lv[ks][1] = *(const f32x4*)(ln_b + kb + 4);
    }

    const bf16x8* __restrict__ Bpv = (const bf16x8*)Bp;
    float* probs = out;
    float* adj   = out + 3*(size_t)NP;
    const float b3v = b3[0];

    #pragma unroll
    for (int s = 0; s < 4; ++s) {
        const int j16 = jw0 + s*16;

        // B fragments for these 16 pairs (coalesced 16B/lane, L2)
        bf16x8 bfr[4];
        const size_t fb = ((size_t)(j16 >> 4))*4;
        #pragma unroll
        for (int ks = 0; ks < 4; ++ks) bfr[ks] = Bpv[(fb + ks)*64 + lane];

        // dot(A[i], B[j_p]) via broadcast-A MFMA, 2 chains of 2
        f32x4 d0 = (f32x4){0.f,0.f,0.f,0.f};
        f32x4 d1 = (f32x4){0.f,0.f,0.f,0.f};
        d0 = __builtin_amdgcn_mfma_f32_16x16x32_bf16(abf[0], bfr[0], d0, 0, 0, 0);
        d1 = __builtin_amdgcn_mfma_f32_16x16x32_bf16(abf[1], bfr[1], d1, 0, 0, 0);
        d0 = __builtin_amdgcn_mfma_f32_16x16x32_bf16(abf[2], bfr[2], d0, 0, 0, 0);
        d1 = __builtin_amdgcn_mfma_f32_16x16x32_bf16(abf[3], bfr[3], d1, 0, 0, 0);

        // O(1) LN stats for this lane's pair
        const float2 sbv = sb[j16 + p16];
        const float mu   = (sav.x + sbv.x) * (1.f/HID);
        const float ez2  = (sav.y + sbv.y + 2.f*(d0[0] + d1[0])) * (1.f/HID);
        const float rstd = rsqrtf(ez2 - mu*mu + 1e-5f);
        const float v    = -mu * rstd;

        // zn = relu(c1*z + c2), c1 = g*rstd, c2 = fma(v, g, l); 16 MFMAs (W2 from LDS)
        f32x4 acc[4];
        #pragma unroll
        for (int nt = 0; nt < 4; ++nt) acc[nt] = (f32x4){0.f,0.f,0.f,0.f};
        #pragma unroll
        for (int ks = 0; ks < 4; ++ks) {
            bf16x8 af;
            #pragma unroll
            for (int e = 0; e < 4; ++e) {
                const float c1a = gv[ks][0][e] * rstd;
                const float c1b = gv[ks][1][e] * rstd;
                const float c2a = fmaf(v, gv[ks][0][e], lv[ks][0][e]);
                const float c2b = fmaf(v, gv[ks][1][e], lv[ks][1][e]);
                float z0 = (float)abf[ks][e]   + (float)bfr[ks][e];
                float z1 = (float)abf[ks][4+e] + (float)bfr[ks][4+e];
                af[e]   = (__bf16)fmaxf(fmaf(c1a, z0, c2a), 0.f);
                af[4+e] = (__bf16)fmaxf(fmaf(c1b, z1, c2b), 0.f);
            }
            #pragma unroll
            for (int nt = 0; nt < 4; ++nt) {
                bf16x8 wf = w2s[(ks*4 + nt)*64 + lane];
                acc[nt] = __builtin_amdgcn_mfma_f32_16x16x32_bf16(wf, af, acc[nt], 0, 0, 0);
            }
        }

        // epilogue: lane holds channels (nt*16 + g4*4 + r) of pair p16
        float part = 0.f;
        #pragma unroll
        for (int nt = 0; nt < 4; ++nt) {
            f32x4 b2v = *(const f32x4*)(b2 + nt*16 + g4*4);
            f32x4 w3v = *(const f32x4*)(W3 + nt*16 + g4*4);
            #pragma unroll
            for (int r = 0; r < 4; ++r)
                part = fmaf(fmaxf(acc[nt][r] + b2v[r], 0.f), w3v[r], part);
        }
        part += __shfl_xor(part, 16);
        part += __shfl_xor(part, 32);

        if (g4 == 0) {
            const int j = j16 + p16;
            if (j == i) {
                adj[(size_t)i*NN + i] = 0.f;
            } else if (j > i) {
                const float pr = 1.f / (1.f + __expf(-(part + b3v)));
                const int kpair = i*(NN-1) - (i*(i-1))/2 + (j - i - 1);
                probs[kpair] = pr;
                adj[(size_t)i*NN + j] = pr;
                adj[(size_t)j*NN + i] = pr;
            }
        }
    }
}

extern "C" void kernel_launch(void* const* d_in, const int* in_sizes, int n_in,
                              void* d_out, int out_size, void* d_ws, size_t ws_size,
                              hipStream_t stream) {
    const float* X    = (const float*)d_in[0];
    const float* Wt   = (const float*)d_in[1];
    const float* bt   = (const float*)d_in[2];
    const float* W1   = (const float*)d_in[3];
    const float* b1   = (const float*)d_in[4];
    const float* ln_g = (const float*)d_in[5];
    const float* ln_b = (const float*)d_in[6];
    const float* W2   = (const float*)d_in[7];
    const float* b2   = (const float*)d_in[8];
    const float* W3   = (const float*)d_in[9];
    const float* b3   = (const float*)d_in[10];
    float* out = (float*)d_out;

    float2* sa  = (float2*)d_ws;                       // 16KB
    float2* sb  = sa + NN;                             // 16KB
    __bf16* Abf = (__bf16*)(sb + NN);                  // 512KB
    __bf16* Bp  = Abf + (size_t)NN * HID;              // 512KB (packed)
    __bf16* W2p = Bp  + (size_t)NN * HID;              // 16KB

    precompute_AB<<<NN, HID, 0, stream>>>(X, Wt, bt, W1, b1, Abf, Bp, sa, sb);
    pack_W2<<<1, 256, 0, stream>>>(W2, W2p);
    fill_pi<<<NN-1, 256, 0, stream>>>(out + NP);

    const int nblk = 256 * 36;
    pairs_mfma<<<nblk, 256, 0, stream>>>(Abf, Bp, sa, sb, ln_g, ln_b, W2p, b2, W3, b3, out);
}